// Round 15
// baseline (218.335 us; speedup 1.0000x reference)
//
#include <hip/hip_runtime.h>

#define N_NODES 50000
#define N_EDGES 800000
#define NB_SCAN 196        // ceil(50000 / 256)
#define NODES_PER_GRP 6250 // 50000 / 8 XCD groups
#define BUCKET_CAP 131072  // per-bucket capacity (mean 100000)
#define CAST_BLOCKS 6250   // blocks doing cast/zero in cast_pack_k

typedef unsigned short ushort_t;
typedef __attribute__((ext_vector_type(8))) short  short8v;   // 8 bf16 (4 VGPR) MFMA A/B frag
typedef __attribute__((ext_vector_type(4))) float  float4v;   // MFMA C/D frag
typedef __attribute__((ext_vector_type(4))) unsigned short ushort4v;
typedef __attribute__((ext_vector_type(8))) unsigned short ushort8v;
typedef __attribute__((ext_vector_type(4))) int int4v;

__device__ __forceinline__ ushort_t f2bf(float f) {
    unsigned u = __float_as_uint(f);
    unsigned r = 0x7fffu + ((u >> 16) & 1u);   // round-to-nearest-even
    return (ushort_t)((u + r) >> 16);
}
__device__ __forceinline__ float bf2f(ushort_t h) {
    return __uint_as_float((unsigned)h << 16);
}

// ---------------- fused: cast x->bf16 + zero bcur  |  pack weights (independent work) ----------------
__global__ __launch_bounds__(256) void cast_pack_k(const float* __restrict__ x,
                                                   ushort_t* __restrict__ xb,
                                                   int* __restrict__ bcur,
                                                   const float* __restrict__ W0n, const float* __restrict__ W0s,
                                                   const float* __restrict__ W1n, const float* __restrict__ W1s,
                                                   const float* __restrict__ W2n, const float* __restrict__ W2s,
                                                   ushort_t* __restrict__ P) {
    const int b = blockIdx.x, t = threadIdx.x;
    if (b < CAST_BLOCKS) {
        int i = b * 256 + t;
        if (i < N_NODES * 32) {
            float4 v = ((const float4*)x)[i];
            ushort4v h;
            h[0] = f2bf(v.x); h[1] = f2bf(v.y); h[2] = f2bf(v.z); h[3] = f2bf(v.w);
            ((ushort4v*)xb)[i] = h;
        }
        if (i < 8) bcur[i] = 0;
        return;
    }
    // weight packing: fp32 W[128][DOUT] -> bf16 MFMA B-fragment layout
    int tid = (b - CAST_BLOCKS) * 256 + t;   // 0..10239
    const float* W; int dout; int base; int r;
    if      (tid < 2048)  { W = W0n; dout = 128; base = 0;     r = tid; }
    else if (tid < 4096)  { W = W0s; dout = 128; base = 16384; r = tid - 2048; }
    else if (tid < 6144)  { W = W1n; dout = 128; base = 32768; r = tid - 4096; }
    else if (tid < 8192)  { W = W1s; dout = 128; base = 49152; r = tid - 6144; }
    else if (tid < 9216)  { W = W2n; dout = 64;  base = 65536; r = tid - 8192; }
    else                  { W = W2s; dout = 64;  base = 73728; r = tid - 9216; }
    int lane = r & 63;
    int ks = (r >> 6) & 3;
    int nt = r >> 8;
    int col = nt * 16 + (lane & 15);
    int k0 = ks * 32 + ((lane >> 4) << 3);
    ushort_t* d = P + (size_t)base + (size_t)r * 8;
    ushort4v lo4, hi4;
#pragma unroll
    for (int j = 0; j < 4; ++j) lo4[j] = f2bf(W[(size_t)(k0 + j) * dout + col]);
#pragma unroll
    for (int j = 0; j < 4; ++j) hi4[j] = f2bf(W[(size_t)(k0 + 4 + j) * dout + col]);
    *(ushort4v*)d = lo4;
    *(ushort4v*)(d + 4) = hi4;
}

// ---------------- edge bucketing: 782 blocks x 4 edges/thread, NO degree atomics ----------------
// (deg comes from the atomic-free LDS histogram over buckets, deg_hist_k below)
__global__ __launch_bounds__(256) void bucket_k(const int4v* __restrict__ dst4,
                                                const int4v* __restrict__ src4,
                                                int* __restrict__ bcur,
                                                int2* __restrict__ buckets) {
    __shared__ int lcount[8];
    __shared__ int lbase[8];
    const int t = threadIdx.x, b = blockIdx.x;
    if (t < 8) lcount[t] = 0;
    __syncthreads();

    const int idx = b * 256 + t;   // int4 index, n4 = 200000
    int4v d, s;
    if (idx < N_EDGES / 4) {
        d = __builtin_nontemporal_load(dst4 + idx);
        s = __builtin_nontemporal_load(src4 + idx);
    } else {
        d[0] = d[1] = d[2] = d[3] = -1;
        s[0] = s[1] = s[2] = s[3] = 0;
    }
    int g[4], li[4];
#pragma unroll
    for (int j = 0; j < 4; ++j) {
        int dv = d[j];
        g[j] = (dv >= 0) ? (dv / NODES_PER_GRP) : -1;
        li[j] = (g[j] >= 0) ? atomicAdd(&lcount[g[j]], 1) : 0;
    }
    __syncthreads();
    if (t < 8) lbase[t] = atomicAdd(bcur + t, lcount[t]);
    __syncthreads();
#pragma unroll
    for (int j = 0; j < 4; ++j) {
        if (g[j] >= 0) {
            int pos = lbase[g[j]] + li[j];
            buckets[(size_t)g[j] * BUCKET_CAP + pos] = make_int2(d[j], s[j]);
        }
    }
}

// ---------------- atomic-free degree: one block per group, 6250-entry LDS histogram ----------------
// Group g's bucket only contains dst in [g*6250,(g+1)*6250) -> 25KB LDS histogram;
// global deg written coalesced by the single owning block (no global atomics at all).
__global__ __launch_bounds__(1024) void deg_hist_k(const int* __restrict__ bcur,
                                                   const int2* __restrict__ buckets,
                                                   int* __restrict__ deg) {
    __shared__ int hist[NODES_PER_GRP];
    const int g = blockIdx.x;
    const int t = threadIdx.x;
    const int lo = g * NODES_PER_GRP;
    const int cnt = bcur[g];
    const int2* bk = buckets + (size_t)g * BUCKET_CAP;
    for (int i = t; i < NODES_PER_GRP; i += 1024) hist[i] = 0;
    __syncthreads();
    for (int i = t; i < cnt; i += 1024) {
        atomicAdd(&hist[bk[i].x - lo], 1);
    }
    __syncthreads();
    for (int i = t; i < NODES_PER_GRP; i += 1024) deg[lo + i] = hist[i];
}

// ---------------- per-256-chunk sums ----------------
__global__ __launch_bounds__(256) void block_sum_k(const int* __restrict__ deg,
                                                   int* __restrict__ bsum, int n) {
    __shared__ int s[256];
    int t = threadIdx.x, b = blockIdx.x;
    int i = b * 256 + t;
    s[t] = (i < n) ? deg[i] : 0;
    __syncthreads();
#pragma unroll
    for (int off = 128; off > 0; off >>= 1) {
        if (t < off) s[t] += s[t + off];
        __syncthreads();
    }
    if (t == 0) bsum[b] = s[0];
}

// ---------------- fused rowptr: every block redundantly scans the 196 chunk sums (LDS, 8 steps),
// takes its own prefix, then scans its deg chunk -> rowptr/cursor/inv ----------------
__global__ __launch_bounds__(256) void rowptr_fused_k(const int* __restrict__ deg,
                                                      const int* __restrict__ bsum,
                                                      int* __restrict__ rowptr,
                                                      int* __restrict__ cursor,
                                                      float* __restrict__ inv) {
    __shared__ int sb[256];
    __shared__ int s[256];
    const int t = threadIdx.x, b = blockIdx.x;
    int v = (t < NB_SCAN) ? bsum[t] : 0;
    sb[t] = v;
    __syncthreads();
#pragma unroll
    for (int off = 1; off < 256; off <<= 1) {
        int u = (t >= off) ? sb[t - off] : 0;
        __syncthreads();
        sb[t] += u;
        __syncthreads();
    }
    const int boffb = (b == 0) ? 0 : sb[b - 1];
    if (b == NB_SCAN - 1 && t == 0) rowptr[N_NODES] = sb[NB_SCAN - 1];

    int i = b * 256 + t;
    int d = (i < N_NODES) ? deg[i] : 0;
    s[t] = d;
    __syncthreads();
#pragma unroll
    for (int off = 1; off < 256; off <<= 1) {
        int u = (t >= off) ? s[t - off] : 0;
        __syncthreads();
        s[t] += u;
        __syncthreads();
    }
    if (i < N_NODES) {
        int r = boffb + s[t] - d;
        rowptr[i] = r;
        cursor[i] = r;
        inv[i] = 1.0f / fmaxf((float)d, 1.0f);
    }
}

// ---------------- scatter from buckets: group g reads ONLY bucket g; csr/cursor slices stay L2-local ----------------
__global__ __launch_bounds__(256) void scatter_bucket_k(const int* __restrict__ bcur,
                                                        const int2* __restrict__ buckets,
                                                        int* __restrict__ cursor,
                                                        int* __restrict__ csr) {
    const int grp = blockIdx.x & 7;
    const int cnt = bcur[grp];
    const int2* bk = buckets + (size_t)grp * BUCKET_CAP;
    const int stride = (gridDim.x >> 3) * 256;
    for (int i = (blockIdx.x >> 3) * 256 + threadIdx.x; i < cnt; i += stride) {
        int2 e = bk[i];
        csr[atomicAdd(cursor + e.x, 1)] = e.y;
    }
}

// ---------------- gather-mean: m[v] = bf16( inv[v] * sum_j h[csr[j]] )  (128-wide bf16) ----------------
// 16 lanes per node (ushort8 = 16B/lane), 4 nodes per wave, 4-edge unroll -> 16 rows in flight/wave.
// m is written nontemporal (single consumer) to keep gather-source h lines resident in L2.
__global__ __launch_bounds__(256) void aggm_k(const ushort_t* __restrict__ h,
                                              const int* __restrict__ rowptr,
                                              const int* __restrict__ csr,
                                              const float* __restrict__ inv,
                                              ushort_t* __restrict__ m, int N) {
    int node = (blockIdx.x * 256 + threadIdx.x) >> 4;
    int c = threadIdx.x & 15;
    if (node >= N) return;
    int start = rowptr[node], end = rowptr[node + 1];

    const ushort8v* hp = (const ushort8v*)h;   // row stride 16 (256 B)
    float a0[8] = {}, a1[8] = {}, a2[8] = {}, a3[8] = {};
    int j = start;
    for (; j + 3 < end; j += 4) {
        int u0 = csr[j], u1 = csr[j + 1], u2 = csr[j + 2], u3 = csr[j + 3];
        ushort8v w0 = hp[(size_t)u0 * 16 + c];
        ushort8v w1 = hp[(size_t)u1 * 16 + c];
        ushort8v w2 = hp[(size_t)u2 * 16 + c];
        ushort8v w3 = hp[(size_t)u3 * 16 + c];
#pragma unroll
        for (int k = 0; k < 8; ++k) {
            a0[k] += bf2f(w0[k]); a1[k] += bf2f(w1[k]);
            a2[k] += bf2f(w2[k]); a3[k] += bf2f(w3[k]);
        }
    }
    for (; j < end; ++j) {
        ushort8v w = hp[(size_t)csr[j] * 16 + c];
#pragma unroll
        for (int k = 0; k < 8; ++k) a0[k] += bf2f(w[k]);
    }
    float s = inv[node];
    ushort8v o;
#pragma unroll
    for (int k = 0; k < 8; ++k) o[k] = f2bf(((a0[k] + a1[k]) + (a2[k] + a3[k])) * s);
    __builtin_nontemporal_store(o, (ushort8v*)m + (size_t)node * 16 + c);
}

// ---------------- fused dual-A GEMM: Out = bf16(relu(H@Ws + M@Wn + b))  [128 -> 128] ----------------
// 64-row tile, 4 waves x 16 rows, 32KB LDS -> 4 blocks/CU. M staged with nontemporal loads (single use).
__global__ __launch_bounds__(256, 4) void fusedgemm_k(const ushort_t* __restrict__ H,
                                                      const ushort_t* __restrict__ M,
                                                      const short8v* __restrict__ Ws,
                                                      const short8v* __restrict__ Wn,
                                                      const float* __restrict__ bias,
                                                      ushort_t* __restrict__ Out, int N) {
    __shared__ ushort_t sm[2][64 * 128];   // 2 x 16 KB
    char* sbH = (char*)sm[0];
    char* sbM = (char*)sm[1];
    const int bm = blockIdx.x * 64;
    const int t = threadIdx.x;
    const int w = t >> 6, l = t & 63;

    {
        const ushort8v* Hp = (const ushort8v*)H;
        const ushort8v* Mp = (const ushort8v*)M;
        ushort8v zeroV = {0, 0, 0, 0, 0, 0, 0, 0};
#pragma unroll
        for (int it = 0; it < 4; ++it) {
            int r = it * 16 + (t >> 4);
            int row = bm + r;
            int byte = (r * 256 + (t & 15) * 16) ^ ((r & 7) << 4);
            ushort8v vh = zeroV, vm = zeroV;
            if (row < N) {
                vh = Hp[(size_t)row * 16 + (t & 15)];
                vm = __builtin_nontemporal_load(Mp + (size_t)row * 16 + (t & 15));
            }
            *(ushort8v*)(sbH + byte) = vh;
            *(ushort8v*)(sbM + byte) = vm;
        }
    }
    __syncthreads();

    float bv[8];
#pragma unroll
    for (int nt = 0; nt < 8; ++nt) bv[nt] = bias[nt * 16 + (l & 15)];

    float4v acc[8] = {};
#pragma unroll
    for (int ks = 0; ks < 4; ++ks) {
        int r0 = w * 16 + (l & 15);
        int b0 = (r0 * 256 + ks * 64 + (l >> 4) * 16) ^ ((r0 & 7) << 4);
        short8v ah = *(const short8v*)(sbH + b0);
        short8v am = *(const short8v*)(sbM + b0);
#pragma unroll
        for (int nt = 0; nt < 8; ++nt) {
            short8v bs = Ws[(nt * 4 + ks) * 64 + l];
            short8v bn = Wn[(nt * 4 + ks) * 64 + l];
            acc[nt] = __builtin_amdgcn_mfma_f32_16x16x32_bf16(ah, bs, acc[nt], 0, 0, 0);
            acc[nt] = __builtin_amdgcn_mfma_f32_16x16x32_bf16(am, bn, acc[nt], 0, 0, 0);
        }
    }

    // C/D layout: col = lane&15, row = (lane>>4)*4 + i  [verified m89]
#pragma unroll
    for (int i = 0; i < 4; ++i) {
        int row = bm + w * 16 + (l >> 4) * 4 + i;
        if (row < N) {
#pragma unroll
            for (int nt = 0; nt < 8; ++nt) {
                int col = nt * 16 + (l & 15);
                Out[(size_t)row * 128 + col] = f2bf(fmaxf(acc[nt][i] + bv[nt], 0.f));
            }
        }
    }
}

// ---------------- layer-2 dual GEMM: S(fp32,->out) = H@Wself + b ; Z(bf16) = H@Wneigh  [128 -> 64] ----------------
__global__ __launch_bounds__(256, 4) void dual64_k(const ushort_t* __restrict__ A,
                                                   const short8v* __restrict__ Wn,
                                                   const short8v* __restrict__ Ws,
                                                   const float* __restrict__ bias,
                                                   ushort_t* __restrict__ Z,
                                                   float* __restrict__ S, int N) {
    constexpr int NT = 4;
    __shared__ ushort_t Asm[64 * 128];   // 16 KB
    char* sb = (char*)Asm;
    const int bm = blockIdx.x * 64;
    const int t = threadIdx.x;
    const int w = t >> 6, l = t & 63;

    {
        const ushort8v* Ap = (const ushort8v*)A;
        ushort8v zeroV = {0, 0, 0, 0, 0, 0, 0, 0};
#pragma unroll
        for (int it = 0; it < 4; ++it) {
            int r = it * 16 + (t >> 4);
            int row = bm + r;
            ushort8v v = zeroV;
            if (row < N) v = Ap[(size_t)row * 16 + (t & 15)];
            int byte = (r * 256 + (t & 15) * 16) ^ ((r & 7) << 4);
            *(ushort8v*)(sb + byte) = v;
        }
    }
    __syncthreads();

    float bv[NT];
#pragma unroll
    for (int nt = 0; nt < NT; ++nt) bv[nt] = bias[nt * 16 + (l & 15)];

    float4v accS[NT] = {}, accN[NT] = {};
#pragma unroll
    for (int ks = 0; ks < 4; ++ks) {
        int r0 = w * 16 + (l & 15);
        int b0 = (r0 * 256 + ks * 64 + (l >> 4) * 16) ^ ((r0 & 7) << 4);
        short8v a = *(const short8v*)(sb + b0);
#pragma unroll
        for (int nt = 0; nt < NT; ++nt) {
            short8v bs = Ws[(nt * 4 + ks) * 64 + l];
            short8v bn = Wn[(nt * 4 + ks) * 64 + l];
            accS[nt] = __builtin_amdgcn_mfma_f32_16x16x32_bf16(a, bs, accS[nt], 0, 0, 0);
            accN[nt] = __builtin_amdgcn_mfma_f32_16x16x32_bf16(a, bn, accN[nt], 0, 0, 0);
        }
    }

#pragma unroll
    for (int i = 0; i < 4; ++i) {
        int row = bm + w * 16 + (l >> 4) * 4 + i;
        if (row < N) {
#pragma unroll
            for (int nt = 0; nt < NT; ++nt) {
                int col = nt * 16 + (l & 15);
                S[(size_t)row * 64 + col] = accS[nt][i] + bv[nt];
                Z[(size_t)row * 64 + col] = f2bf(accN[nt][i]);
            }
        }
    }
}

// ---------------- layer-2 aggregation: out(fp32,=S) += inv * sum z[nbr]  (64-wide) ----------------
// 8 lanes per node (ushort8 = 16B/lane), 8 nodes per wave, 4-edge unroll -> 32 rows in flight/wave.
__global__ __launch_bounds__(256) void agg64_k(const ushort_t* __restrict__ z,
                                               const int* __restrict__ rowptr,
                                               const int* __restrict__ csr,
                                               const float* __restrict__ inv,
                                               float* __restrict__ out, int N) {
    int node = (blockIdx.x * 256 + threadIdx.x) >> 3;
    int c = threadIdx.x & 7;
    if (node >= N) return;
    int start = rowptr[node], end = rowptr[node + 1];

    const ushort8v* zp = (const ushort8v*)z;   // row stride 8 (128 B)
    float a0[8] = {}, a1[8] = {}, a2[8] = {}, a3[8] = {};
    int j = start;
    for (; j + 3 < end; j += 4) {
        int u0 = csr[j], u1 = csr[j + 1], u2 = csr[j + 2], u3 = csr[j + 3];
        ushort8v w0 = zp[(size_t)u0 * 8 + c];
        ushort8v w1 = zp[(size_t)u1 * 8 + c];
        ushort8v w2 = zp[(size_t)u2 * 8 + c];
        ushort8v w3 = zp[(size_t)u3 * 8 + c];
#pragma unroll
        for (int k = 0; k < 8; ++k) {
            a0[k] += bf2f(w0[k]); a1[k] += bf2f(w1[k]);
            a2[k] += bf2f(w2[k]); a3[k] += bf2f(w3[k]);
        }
    }
    for (; j < end; ++j) {
        ushort8v w = zp[(size_t)csr[j] * 8 + c];
#pragma unroll
        for (int k = 0; k < 8; ++k) a0[k] += bf2f(w[k]);
    }
    float s = inv[node];
    float* op = out + (size_t)node * 64 + c * 8;
    float4 o0 = *(float4*)op;
    float4 o1 = *(float4*)(op + 4);
    o0.x += ((a0[0] + a1[0]) + (a2[0] + a3[0])) * s;
    o0.y += ((a0[1] + a1[1]) + (a2[1] + a3[1])) * s;
    o0.z += ((a0[2] + a1[2]) + (a2[2] + a3[2])) * s;
    o0.w += ((a0[3] + a1[3]) + (a2[3] + a3[3])) * s;
    o1.x += ((a0[4] + a1[4]) + (a2[4] + a3[4])) * s;
    o1.y += ((a0[5] + a1[5]) + (a2[5] + a3[5])) * s;
    o1.z += ((a0[6] + a1[6]) + (a2[6] + a3[6])) * s;
    o1.w += ((a0[7] + a1[7]) + (a2[7] + a3[7])) * s;
    *(float4*)op = o0;
    *(float4*)(op + 4) = o1;
}

// ---------------- launch ----------------

extern "C" void kernel_launch(void* const* d_in, const int* in_sizes, int n_in,
                              void* d_out, int out_size, void* d_ws, size_t ws_size,
                              hipStream_t stream) {
    const float* x       = (const float*)d_in[0];
    const int*   src     = (const int*)d_in[1];
    const int*   dst     = (const int*)d_in[2];
    const float* Wself0  = (const float*)d_in[3];
    const float* Wneigh0 = (const float*)d_in[4];
    const float* b0      = (const float*)d_in[5];
    const float* Wself1  = (const float*)d_in[6];
    const float* Wneigh1 = (const float*)d_in[7];
    const float* b1      = (const float*)d_in[8];
    const float* Wself2  = (const float*)d_in[9];
    const float* Wneigh2 = (const float*)d_in[10];
    const float* b2      = (const float*)d_in[11];
    float* out = (float*)d_out;

    char* ws = (char*)d_ws;
    size_t off = 0;
    auto alloc = [&](size_t bytes) -> void* {
        void* p = ws + off;
        off += (bytes + 255) & ~(size_t)255;
        return p;
    };
    int*      deg     = (int*)alloc((size_t)N_NODES * 4);
    float*    inv     = (float*)alloc((size_t)N_NODES * 4);
    int*      rowptr  = (int*)alloc((size_t)(N_NODES + 1) * 4);
    int*      cursor  = (int*)alloc((size_t)N_NODES * 4);
    int*      csr     = (int*)alloc((size_t)N_EDGES * 4);
    int*      bsum    = (int*)alloc((size_t)NB_SCAN * 4);
    int*      bcur    = (int*)alloc((size_t)8 * 4);
    int2*     buckets = (int2*)alloc((size_t)8 * BUCKET_CAP * 8);
    ushort_t* packW   = (ushort_t*)alloc((size_t)81920 * 2);
    ushort_t* xb      = (ushort_t*)alloc((size_t)N_NODES * 128 * 2);
    ushort_t* mbuf    = (ushort_t*)alloc((size_t)N_NODES * 128 * 2);
    ushort_t* h1      = (ushort_t*)alloc((size_t)N_NODES * 128 * 2);
    ushort_t* h2      = (ushort_t*)alloc((size_t)N_NODES * 128 * 2);
    ushort_t* z64     = (ushort_t*)alloc((size_t)N_NODES * 64 * 2);

    dim3 b256(256);
    const int gemmBlocks   = (N_NODES + 63) / 64;          // 782 (64-row tiles, 4 blocks/CU)
    const int aggmBlocks   = (N_NODES * 16 + 255) / 256;   // 3125
    const int agg64Blocks  = (N_NODES * 8 + 255) / 256;    // 1563
    const int bucketBlocks = (N_EDGES / 4 + 255) / 256;    // 782 (4 edges/thread)

    // ---- CSR build: cast+pack | bucket | LDS-hist deg (atomic-free) | chunk sums | rowptr | scatter ----
    cast_pack_k<<<CAST_BLOCKS + 40, b256, 0, stream>>>(x, xb, bcur,
                                                       Wneigh0, Wself0, Wneigh1, Wself1,
                                                       Wneigh2, Wself2, packW);
    bucket_k<<<bucketBlocks, b256, 0, stream>>>((const int4v*)dst, (const int4v*)src,
                                                bcur, buckets);
    deg_hist_k<<<8, dim3(1024), 0, stream>>>(bcur, buckets, deg);
    block_sum_k<<<NB_SCAN, b256, 0, stream>>>(deg, bsum, N_NODES);
    rowptr_fused_k<<<NB_SCAN, b256, 0, stream>>>(deg, bsum, rowptr, cursor, inv);
    scatter_bucket_k<<<512, b256, 0, stream>>>(bcur, buckets, cursor, csr);

    const short8v* pN0 = (const short8v*)(packW);
    const short8v* pS0 = (const short8v*)(packW + 16384);
    const short8v* pN1 = (const short8v*)(packW + 32768);
    const short8v* pS1 = (const short8v*)(packW + 49152);
    const short8v* pN2 = (const short8v*)(packW + 65536);
    const short8v* pS2 = (const short8v*)(packW + 73728);

    // layer 0 (agg-first): m = mean(xb[nbr]); h1 = relu(xb@Ws0 + m@Wn0 + b0)
    aggm_k<<<aggmBlocks, b256, 0, stream>>>(xb, rowptr, csr, inv, mbuf, N_NODES);
    fusedgemm_k<<<gemmBlocks, b256, 0, stream>>>(xb, mbuf, pS0, pN0, b0, h1, N_NODES);

    // layer 1 (agg-first): m = mean(h1[nbr]); h2 = relu(h1@Ws1 + m@Wn1 + b1)
    aggm_k<<<aggmBlocks, b256, 0, stream>>>(h1, rowptr, csr, inv, mbuf, N_NODES);
    fusedgemm_k<<<gemmBlocks, b256, 0, stream>>>(h1, mbuf, pS1, pN1, b1, h2, N_NODES);

    // layer 2 (gemm-first): out = h2@Ws2 + b2 ; z = bf16(h2@Wn2) ; out += inv*segsum(z)
    dual64_k<<<gemmBlocks, b256, 0, stream>>>(h2, pN2, pS2, b2, z64, out, N_NODES);
    agg64_k<<<agg64Blocks, b256, 0, stream>>>(z64, rowptr, csr, inv, out, N_NODES);
}

// Round 16
// 211.667 us; speedup vs baseline: 1.0315x; 1.0315x over previous
//
#include <hip/hip_runtime.h>

#define N_NODES 50000
#define N_EDGES 800000
#define NB_SCAN 196        // total 256-chunks = 7*25 + 21
#define NODES_PER_GRP 6400 // chunk-aligned (25 chunks of 256); groups 0..7, last has 5200
#define CHUNKS_PER_GRP 25
#define BUCKET_CAP 131072  // per-bucket capacity (mean ~102400)
#define CAST_BLOCKS 6250   // blocks doing cast/zero in cast_pack_k

typedef unsigned short ushort_t;
typedef __attribute__((ext_vector_type(8))) short  short8v;   // 8 bf16 (4 VGPR) MFMA A/B frag
typedef __attribute__((ext_vector_type(4))) float  float4v;   // MFMA C/D frag
typedef __attribute__((ext_vector_type(4))) unsigned short ushort4v;
typedef __attribute__((ext_vector_type(8))) unsigned short ushort8v;
typedef __attribute__((ext_vector_type(4))) int int4v;

__device__ __forceinline__ ushort_t f2bf(float f) {
    unsigned u = __float_as_uint(f);
    unsigned r = 0x7fffu + ((u >> 16) & 1u);   // round-to-nearest-even
    return (ushort_t)((u + r) >> 16);
}
__device__ __forceinline__ float bf2f(ushort_t h) {
    return __uint_as_float((unsigned)h << 16);
}

// ---------------- fused: cast x->bf16 + zero bcur  |  pack weights (independent work) ----------------
__global__ __launch_bounds__(256) void cast_pack_k(const float* __restrict__ x,
                                                   ushort_t* __restrict__ xb,
                                                   int* __restrict__ bcur,
                                                   const float* __restrict__ W0n, const float* __restrict__ W0s,
                                                   const float* __restrict__ W1n, const float* __restrict__ W1s,
                                                   const float* __restrict__ W2n, const float* __restrict__ W2s,
                                                   ushort_t* __restrict__ P) {
    const int b = blockIdx.x, t = threadIdx.x;
    if (b < CAST_BLOCKS) {
        int i = b * 256 + t;
        if (i < N_NODES * 32) {
            float4 v = ((const float4*)x)[i];
            ushort4v h;
            h[0] = f2bf(v.x); h[1] = f2bf(v.y); h[2] = f2bf(v.z); h[3] = f2bf(v.w);
            ((ushort4v*)xb)[i] = h;
        }
        if (i < 8) bcur[i] = 0;
        return;
    }
    // weight packing: fp32 W[128][DOUT] -> bf16 MFMA B-fragment layout
    int tid = (b - CAST_BLOCKS) * 256 + t;   // 0..10239
    const float* W; int dout; int base; int r;
    if      (tid < 2048)  { W = W0n; dout = 128; base = 0;     r = tid; }
    else if (tid < 4096)  { W = W0s; dout = 128; base = 16384; r = tid - 2048; }
    else if (tid < 6144)  { W = W1n; dout = 128; base = 32768; r = tid - 4096; }
    else if (tid < 8192)  { W = W1s; dout = 128; base = 49152; r = tid - 6144; }
    else if (tid < 9216)  { W = W2n; dout = 64;  base = 65536; r = tid - 8192; }
    else                  { W = W2s; dout = 64;  base = 73728; r = tid - 9216; }
    int lane = r & 63;
    int ks = (r >> 6) & 3;
    int nt = r >> 8;
    int col = nt * 16 + (lane & 15);
    int k0 = ks * 32 + ((lane >> 4) << 3);
    ushort_t* d = P + (size_t)base + (size_t)r * 8;
    ushort4v lo4, hi4;
#pragma unroll
    for (int j = 0; j < 4; ++j) lo4[j] = f2bf(W[(size_t)(k0 + j) * dout + col]);
#pragma unroll
    for (int j = 0; j < 4; ++j) hi4[j] = f2bf(W[(size_t)(k0 + 4 + j) * dout + col]);
    *(ushort4v*)d = lo4;
    *(ushort4v*)(d + 4) = hi4;
}

// ---------------- edge bucketing: 782 blocks x 4 edges/thread ----------------
__global__ __launch_bounds__(256) void bucket_k(const int4v* __restrict__ dst4,
                                                const int4v* __restrict__ src4,
                                                int* __restrict__ bcur,
                                                int2* __restrict__ buckets) {
    __shared__ int lcount[8];
    __shared__ int lbase[8];
    const int t = threadIdx.x, b = blockIdx.x;
    if (t < 8) lcount[t] = 0;
    __syncthreads();

    const int idx = b * 256 + t;   // int4 index, n4 = 200000
    int4v d, s;
    if (idx < N_EDGES / 4) {
        d = __builtin_nontemporal_load(dst4 + idx);
        s = __builtin_nontemporal_load(src4 + idx);
    } else {
        d[0] = d[1] = d[2] = d[3] = -1;
        s[0] = s[1] = s[2] = s[3] = 0;
    }
    int g[4], li[4];
#pragma unroll
    for (int j = 0; j < 4; ++j) {
        int dv = d[j];
        g[j] = (dv >= 0) ? (dv / NODES_PER_GRP) : -1;
        li[j] = (g[j] >= 0) ? atomicAdd(&lcount[g[j]], 1) : 0;
    }
    __syncthreads();
    if (t < 8) lbase[t] = atomicAdd(bcur + t, lcount[t]);
    __syncthreads();
#pragma unroll
    for (int j = 0; j < 4; ++j) {
        if (g[j] >= 0) {
            int pos = lbase[g[j]] + li[j];
            buckets[(size_t)g[j] * BUCKET_CAP + pos] = make_int2(d[j], s[j]);
        }
    }
}

// ---------------- atomic-free degree + chunk sums: one block per group, LDS histogram ----------------
// Group g's bucket only contains dst in [g*6400,(g+1)*6400) -> 25.6KB LDS histogram.
// Writes deg coalesced AND the 256-chunk sums (group boundary is chunk-aligned) -> block_sum_k deleted.
__global__ __launch_bounds__(1024) void deg_hist_k(const int* __restrict__ bcur,
                                                   const int2* __restrict__ buckets,
                                                   int* __restrict__ deg,
                                                   int* __restrict__ bsum) {
    __shared__ int hist[NODES_PER_GRP];
    const int g = blockIdx.x;
    const int t = threadIdx.x;
    const int lo = g * NODES_PER_GRP;
    const int cnt = bcur[g];
    const int2* bk = buckets + (size_t)g * BUCKET_CAP;
    for (int i = t; i < NODES_PER_GRP; i += 1024) hist[i] = 0;
    __syncthreads();
    for (int i = t; i < cnt; i += 1024) {
        atomicAdd(&hist[bk[i].x - lo], 1);
    }
    __syncthreads();
    const int nNodes = (N_NODES - lo < NODES_PER_GRP) ? (N_NODES - lo) : NODES_PER_GRP;
    for (int i = t; i < nNodes; i += 1024) deg[lo + i] = hist[i];
    // chunk sums from LDS: one wave per 256-chunk (hist beyond nNodes is zero)
    const int wave = t >> 6, lane = t & 63;
    const int nch = (nNodes + 255) >> 8;
    for (int c = wave; c < nch; c += 16) {
        int base = c * 256 + lane;
        int s = hist[base] + hist[base + 64] + hist[base + 128] + hist[base + 192];
#pragma unroll
        for (int off = 32; off > 0; off >>= 1) s += __shfl_xor(s, off);
        if (lane == 0) bsum[g * CHUNKS_PER_GRP + c] = s;
    }
}

// ---------------- fused rowptr: every block redundantly scans the 196 chunk sums (LDS, 8 steps),
// takes its own prefix, then scans its deg chunk -> rowptr/cursor/inv ----------------
__global__ __launch_bounds__(256) void rowptr_fused_k(const int* __restrict__ deg,
                                                      const int* __restrict__ bsum,
                                                      int* __restrict__ rowptr,
                                                      int* __restrict__ cursor,
                                                      float* __restrict__ inv) {
    __shared__ int sb[256];
    __shared__ int s[256];
    const int t = threadIdx.x, b = blockIdx.x;
    int v = (t < NB_SCAN) ? bsum[t] : 0;
    sb[t] = v;
    __syncthreads();
#pragma unroll
    for (int off = 1; off < 256; off <<= 1) {
        int u = (t >= off) ? sb[t - off] : 0;
        __syncthreads();
        sb[t] += u;
        __syncthreads();
    }
    const int boffb = (b == 0) ? 0 : sb[b - 1];
    if (b == NB_SCAN - 1 && t == 0) rowptr[N_NODES] = sb[NB_SCAN - 1];

    int i = b * 256 + t;
    int d = (i < N_NODES) ? deg[i] : 0;
    s[t] = d;
    __syncthreads();
#pragma unroll
    for (int off = 1; off < 256; off <<= 1) {
        int u = (t >= off) ? s[t - off] : 0;
        __syncthreads();
        s[t] += u;
        __syncthreads();
    }
    if (i < N_NODES) {
        int r = boffb + s[t] - d;
        rowptr[i] = r;
        cursor[i] = r;
        inv[i] = 1.0f / fmaxf((float)d, 1.0f);
    }
}

// ---------------- scatter from buckets: group g reads ONLY bucket g ----------------
__global__ __launch_bounds__(256) void scatter_bucket_k(const int* __restrict__ bcur,
                                                        const int2* __restrict__ buckets,
                                                        int* __restrict__ cursor,
                                                        int* __restrict__ csr) {
    const int grp = blockIdx.x & 7;
    const int cnt = bcur[grp];
    const int2* bk = buckets + (size_t)grp * BUCKET_CAP;
    const int stride = (gridDim.x >> 3) * 256;
    for (int i = (blockIdx.x >> 3) * 256 + threadIdx.x; i < cnt; i += stride) {
        int2 e = bk[i];
        csr[atomicAdd(cursor + e.x, 1)] = e.y;
    }
}

// ---------------- FUSED gather-mean + dual-A GEMM: Out = bf16(relu(H@Ws + mean@Wn + b)) ----------------
// Block owns 64 rows. Gather-mean is computed directly into the swizzled LDS M-tile (no mbuf,
// no separate aggm dispatch); gather of one block overlaps MFMA of others (separate pipes).
__global__ __launch_bounds__(256, 4) void gathergemm_k(const ushort_t* __restrict__ H,
                                                       const int* __restrict__ rowptr,
                                                       const int* __restrict__ csr,
                                                       const float* __restrict__ inv,
                                                       const short8v* __restrict__ Ws,
                                                       const short8v* __restrict__ Wn,
                                                       const float* __restrict__ bias,
                                                       ushort_t* __restrict__ Out, int N) {
    __shared__ ushort_t sm[2][64 * 128];   // 2 x 16 KB
    char* sbH = (char*)sm[0];
    char* sbM = (char*)sm[1];
    const int bm = blockIdx.x * 64;
    const int t = threadIdx.x;
    const int w = t >> 6, l = t & 63;
    const ushort8v* Hp = (const ushort8v*)H;   // row stride 16 (256 B)
    ushort8v zeroV = {0, 0, 0, 0, 0, 0, 0, 0};

    // stage H tile (swizzled)
#pragma unroll
    for (int it = 0; it < 4; ++it) {
        int r = it * 16 + (t >> 4);
        int row = bm + r;
        int byte = (r * 256 + (t & 15) * 16) ^ ((r & 7) << 4);
        ushort8v vh = zeroV;
        if (row < N) vh = Hp[(size_t)row * 16 + (t & 15)];
        *(ushort8v*)(sbH + byte) = vh;
    }

    // gather-mean M tile straight into swizzled LDS: 16 lanes per row, lane c owns cols [8c,8c+8)
    const int c = t & 15;
#pragma unroll
    for (int pass = 0; pass < 4; ++pass) {
        int r = pass * 16 + (t >> 4);
        int row = bm + r;
        int byte = (r * 256 + c * 16) ^ ((r & 7) << 4);
        ushort8v o = zeroV;
        if (row < N) {
            int start = rowptr[row], end = rowptr[row + 1];
            float a0[8] = {}, a1[8] = {}, a2[8] = {}, a3[8] = {};
            int j = start;
            for (; j + 3 < end; j += 4) {
                int u0 = csr[j], u1 = csr[j + 1], u2 = csr[j + 2], u3 = csr[j + 3];
                ushort8v w0 = Hp[(size_t)u0 * 16 + c];
                ushort8v w1 = Hp[(size_t)u1 * 16 + c];
                ushort8v w2 = Hp[(size_t)u2 * 16 + c];
                ushort8v w3 = Hp[(size_t)u3 * 16 + c];
#pragma unroll
                for (int k = 0; k < 8; ++k) {
                    a0[k] += bf2f(w0[k]); a1[k] += bf2f(w1[k]);
                    a2[k] += bf2f(w2[k]); a3[k] += bf2f(w3[k]);
                }
            }
            for (; j < end; ++j) {
                ushort8v wv = Hp[(size_t)csr[j] * 16 + c];
#pragma unroll
                for (int k = 0; k < 8; ++k) a0[k] += bf2f(wv[k]);
            }
            float sc = inv[row];
#pragma unroll
            for (int k = 0; k < 8; ++k) o[k] = f2bf(((a0[k] + a1[k]) + (a2[k] + a3[k])) * sc);
        }
        *(ushort8v*)(sbM + byte) = o;
    }
    __syncthreads();

    float bv[8];
#pragma unroll
    for (int nt = 0; nt < 8; ++nt) bv[nt] = bias[nt * 16 + (l & 15)];

    float4v acc[8] = {};
#pragma unroll
    for (int ks = 0; ks < 4; ++ks) {
        int r0 = w * 16 + (l & 15);
        int b0 = (r0 * 256 + ks * 64 + (l >> 4) * 16) ^ ((r0 & 7) << 4);
        short8v ah = *(const short8v*)(sbH + b0);
        short8v am = *(const short8v*)(sbM + b0);
#pragma unroll
        for (int nt = 0; nt < 8; ++nt) {
            short8v bs = Ws[(nt * 4 + ks) * 64 + l];
            short8v bn = Wn[(nt * 4 + ks) * 64 + l];
            acc[nt] = __builtin_amdgcn_mfma_f32_16x16x32_bf16(ah, bs, acc[nt], 0, 0, 0);
            acc[nt] = __builtin_amdgcn_mfma_f32_16x16x32_bf16(am, bn, acc[nt], 0, 0, 0);
        }
    }

    // C/D layout: col = lane&15, row = (lane>>4)*4 + i  [verified m89]
#pragma unroll
    for (int i = 0; i < 4; ++i) {
        int row = bm + w * 16 + (l >> 4) * 4 + i;
        if (row < N) {
#pragma unroll
            for (int nt = 0; nt < 8; ++nt) {
                int col = nt * 16 + (l & 15);
                Out[(size_t)row * 128 + col] = f2bf(fmaxf(acc[nt][i] + bv[nt], 0.f));
            }
        }
    }
}

// ---------------- layer-2 dual GEMM: S(fp32,->out) = H@Wself + b ; Z(bf16) = H@Wneigh  [128 -> 64] ----------------
__global__ __launch_bounds__(256, 4) void dual64_k(const ushort_t* __restrict__ A,
                                                   const short8v* __restrict__ Wn,
                                                   const short8v* __restrict__ Ws,
                                                   const float* __restrict__ bias,
                                                   ushort_t* __restrict__ Z,
                                                   float* __restrict__ S, int N) {
    constexpr int NT = 4;
    __shared__ ushort_t Asm[64 * 128];   // 16 KB
    char* sb = (char*)Asm;
    const int bm = blockIdx.x * 64;
    const int t = threadIdx.x;
    const int w = t >> 6, l = t & 63;

    {
        const ushort8v* Ap = (const ushort8v*)A;
        ushort8v zeroV = {0, 0, 0, 0, 0, 0, 0, 0};
#pragma unroll
        for (int it = 0; it < 4; ++it) {
            int r = it * 16 + (t >> 4);
            int row = bm + r;
            ushort8v v = zeroV;
            if (row < N) v = Ap[(size_t)row * 16 + (t & 15)];
            int byte = (r * 256 + (t & 15) * 16) ^ ((r & 7) << 4);
            *(ushort8v*)(sb + byte) = v;
        }
    }
    __syncthreads();

    float bv[NT];
#pragma unroll
    for (int nt = 0; nt < NT; ++nt) bv[nt] = bias[nt * 16 + (l & 15)];

    float4v accS[NT] = {}, accN[NT] = {};
#pragma unroll
    for (int ks = 0; ks < 4; ++ks) {
        int r0 = w * 16 + (l & 15);
        int b0 = (r0 * 256 + ks * 64 + (l >> 4) * 16) ^ ((r0 & 7) << 4);
        short8v a = *(const short8v*)(sb + b0);
#pragma unroll
        for (int nt = 0; nt < NT; ++nt) {
            short8v bs = Ws[(nt * 4 + ks) * 64 + l];
            short8v bn = Wn[(nt * 4 + ks) * 64 + l];
            accS[nt] = __builtin_amdgcn_mfma_f32_16x16x32_bf16(a, bs, accS[nt], 0, 0, 0);
            accN[nt] = __builtin_amdgcn_mfma_f32_16x16x32_bf16(a, bn, accN[nt], 0, 0, 0);
        }
    }

#pragma unroll
    for (int i = 0; i < 4; ++i) {
        int row = bm + w * 16 + (l >> 4) * 4 + i;
        if (row < N) {
#pragma unroll
            for (int nt = 0; nt < NT; ++nt) {
                int col = nt * 16 + (l & 15);
                S[(size_t)row * 64 + col] = accS[nt][i] + bv[nt];
                Z[(size_t)row * 64 + col] = f2bf(accN[nt][i]);
            }
        }
    }
}

// ---------------- layer-2 aggregation: out(fp32,=S) += inv * sum z[nbr]  (64-wide) ----------------
__global__ __launch_bounds__(256) void agg64_k(const ushort_t* __restrict__ z,
                                               const int* __restrict__ rowptr,
                                               const int* __restrict__ csr,
                                               const float* __restrict__ inv,
                                               float* __restrict__ out, int N) {
    int node = (blockIdx.x * 256 + threadIdx.x) >> 3;
    int c = threadIdx.x & 7;
    if (node >= N) return;
    int start = rowptr[node], end = rowptr[node + 1];

    const ushort8v* zp = (const ushort8v*)z;   // row stride 8 (128 B)
    float a0[8] = {}, a1[8] = {}, a2[8] = {}, a3[8] = {};
    int j = start;
    for (; j + 3 < end; j += 4) {
        int u0 = csr[j], u1 = csr[j + 1], u2 = csr[j + 2], u3 = csr[j + 3];
        ushort8v w0 = zp[(size_t)u0 * 8 + c];
        ushort8v w1 = zp[(size_t)u1 * 8 + c];
        ushort8v w2 = zp[(size_t)u2 * 8 + c];
        ushort8v w3 = zp[(size_t)u3 * 8 + c];
#pragma unroll
        for (int k = 0; k < 8; ++k) {
            a0[k] += bf2f(w0[k]); a1[k] += bf2f(w1[k]);
            a2[k] += bf2f(w2[k]); a3[k] += bf2f(w3[k]);
        }
    }
    for (; j < end; ++j) {
        ushort8v w = zp[(size_t)csr[j] * 8 + c];
#pragma unroll
        for (int k = 0; k < 8; ++k) a0[k] += bf2f(w[k]);
    }
    float s = inv[node];
    float* op = out + (size_t)node * 64 + c * 8;
    float4 o0 = *(float4*)op;
    float4 o1 = *(float4*)(op + 4);
    o0.x += ((a0[0] + a1[0]) + (a2[0] + a3[0])) * s;
    o0.y += ((a0[1] + a1[1]) + (a2[1] + a3[1])) * s;
    o0.z += ((a0[2] + a1[2]) + (a2[2] + a3[2])) * s;
    o0.w += ((a0[3] + a1[3]) + (a2[3] + a3[3])) * s;
    o1.x += ((a0[4] + a1[4]) + (a2[4] + a3[4])) * s;
    o1.y += ((a0[5] + a1[5]) + (a2[5] + a3[5])) * s;
    o1.z += ((a0[6] + a1[6]) + (a2[6] + a3[6])) * s;
    o1.w += ((a0[7] + a1[7]) + (a2[7] + a3[7])) * s;
    *(float4*)op = o0;
    *(float4*)(op + 4) = o1;
}

// ---------------- launch ----------------

extern "C" void kernel_launch(void* const* d_in, const int* in_sizes, int n_in,
                              void* d_out, int out_size, void* d_ws, size_t ws_size,
                              hipStream_t stream) {
    const float* x       = (const float*)d_in[0];
    const int*   src     = (const int*)d_in[1];
    const int*   dst     = (const int*)d_in[2];
    const float* Wself0  = (const float*)d_in[3];
    const float* Wneigh0 = (const float*)d_in[4];
    const float* b0      = (const float*)d_in[5];
    const float* Wself1  = (const float*)d_in[6];
    const float* Wneigh1 = (const float*)d_in[7];
    const float* b1      = (const float*)d_in[8];
    const float* Wself2  = (const float*)d_in[9];
    const float* Wneigh2 = (const float*)d_in[10];
    const float* b2      = (const float*)d_in[11];
    float* out = (float*)d_out;

    char* ws = (char*)d_ws;
    size_t off = 0;
    auto alloc = [&](size_t bytes) -> void* {
        void* p = ws + off;
        off += (bytes + 255) & ~(size_t)255;
        return p;
    };
    int*      deg     = (int*)alloc((size_t)N_NODES * 4);
    float*    inv     = (float*)alloc((size_t)N_NODES * 4);
    int*      rowptr  = (int*)alloc((size_t)(N_NODES + 1) * 4);
    int*      cursor  = (int*)alloc((size_t)N_NODES * 4);
    int*      csr     = (int*)alloc((size_t)N_EDGES * 4);
    int*      bsum    = (int*)alloc((size_t)NB_SCAN * 4);
    int*      bcur    = (int*)alloc((size_t)8 * 4);
    int2*     buckets = (int2*)alloc((size_t)8 * BUCKET_CAP * 8);
    ushort_t* packW   = (ushort_t*)alloc((size_t)81920 * 2);
    ushort_t* xb      = (ushort_t*)alloc((size_t)N_NODES * 128 * 2);
    ushort_t* h1      = (ushort_t*)alloc((size_t)N_NODES * 128 * 2);
    ushort_t* h2      = (ushort_t*)alloc((size_t)N_NODES * 128 * 2);
    ushort_t* z64     = (ushort_t*)alloc((size_t)N_NODES * 64 * 2);

    dim3 b256(256);
    const int gemmBlocks   = (N_NODES + 63) / 64;          // 782 (64-row tiles, 4 blocks/CU)
    const int agg64Blocks  = (N_NODES * 8 + 255) / 256;    // 1563
    const int bucketBlocks = (N_EDGES / 4 + 255) / 256;    // 782 (4 edges/thread)

    // ---- CSR build: cast+pack | bucket | LDS-hist deg+chunk-sums | rowptr | scatter ----
    cast_pack_k<<<CAST_BLOCKS + 40, b256, 0, stream>>>(x, xb, bcur,
                                                       Wneigh0, Wself0, Wneigh1, Wself1,
                                                       Wneigh2, Wself2, packW);
    bucket_k<<<bucketBlocks, b256, 0, stream>>>((const int4v*)dst, (const int4v*)src,
                                                bcur, buckets);
    deg_hist_k<<<8, dim3(1024), 0, stream>>>(bcur, buckets, deg, bsum);
    rowptr_fused_k<<<NB_SCAN, b256, 0, stream>>>(deg, bsum, rowptr, cursor, inv);
    scatter_bucket_k<<<512, b256, 0, stream>>>(bcur, buckets, cursor, csr);

    const short8v* pN0 = (const short8v*)(packW);
    const short8v* pS0 = (const short8v*)(packW + 16384);
    const short8v* pN1 = (const short8v*)(packW + 32768);
    const short8v* pS1 = (const short8v*)(packW + 49152);
    const short8v* pN2 = (const short8v*)(packW + 65536);
    const short8v* pS2 = (const short8v*)(packW + 73728);

    // layer 0 (fused gather+GEMM): h1 = relu(xb@Ws0 + mean(xb[nbr])@Wn0 + b0)
    gathergemm_k<<<gemmBlocks, b256, 0, stream>>>(xb, rowptr, csr, inv, pS0, pN0, b0, h1, N_NODES);

    // layer 1 (fused gather+GEMM): h2 = relu(h1@Ws1 + mean(h1[nbr])@Wn1 + b1)
    gathergemm_k<<<gemmBlocks, b256, 0, stream>>>(h1, rowptr, csr, inv, pS1, pN1, b1, h2, N_NODES);

    // layer 2 (gemm-first): out = h2@Ws2 + b2 ; z = bf16(h2@Wn2) ; out += inv*segsum(z)
    dual64_k<<<gemmBlocks, b256, 0, stream>>>(h2, pN2, pS2, b2, z64, out, N_NODES);
    agg64_k<<<agg64Blocks, b256, 0, stream>>>(z64, rowptr, csr, inv, out, N_NODES);
}